// Round 1
// baseline (74.353 us; speedup 1.0000x reference)
//
#include <hip/hip_runtime.h>
#include <hip/hip_bf16.h>

// MaskedDenseLayerMultiMasks: out[b,m,o] = sum_i x[b,m,i] * kernel[i,o] * masks[m,i,o]
// B=512, M=16, I=O=1024, all fp32. Strategy: per-mask bf16 MFMA GEMM with fused
// fp32->bf16 conversion during LDS staging (reg-staged; global_load_lds can't convert).

#define BATCH 512
#define NMASK 16
#define IN_D  1024
#define OUT_D 1024

#define BM 128
#define BN 128
#define BK 32
#define BKP 40      // padded LDS k-stride (elements): 80B rows -> 2-way (free) b128 reads
#define THREADS 256

using bf16x8 = __attribute__((ext_vector_type(8))) __bf16;
using f32x4  = __attribute__((ext_vector_type(4))) float;

static_assert(sizeof(bf16x8) == 16, "frag size");

__device__ __forceinline__ unsigned short f2bf(float f) {
    unsigned u = __float_as_uint(f);
    u += 0x7fffu + ((u >> 16) & 1u);          // round-to-nearest-even
    return (unsigned short)(u >> 16);
}

__device__ __forceinline__ ushort4 pack4(float a, float b, float c, float d) {
    ushort4 r; r.x = f2bf(a); r.y = f2bf(b); r.z = f2bf(c); r.w = f2bf(d); return r;
}

__global__ void __launch_bounds__(THREADS, 2)
mdl_mfma_kernel(const float* __restrict__ X,   // (B, M, I)
                const float* __restrict__ Kn,  // (I, O)
                const float* __restrict__ Mk,  // (M, I, O)
                float* __restrict__ Out)       // (B, M, O)
{
    __shared__ __align__(16) unsigned short As[BM * BKP];  // As[row][k]
    __shared__ __align__(16) unsigned short Bs[BN * BKP];  // Bs[ocol][k], k XOR-swizzled

    const int t = threadIdx.x;
    const int l = t & 63;          // lane
    const int w = t >> 6;          // wave 0..3

    // XCD-aware bijective swizzle: 512 wgs, 8 XCDs, 64 contiguous wgs per XCD.
    // wg = m*32 + ob*4 + bb  -> each XCD owns 2 masks; bb innermost so the 4
    // batch-blocks sharing one B-tile run back-to-back (L2 temporal locality).
    const int raw = blockIdx.x;
    const int wg  = (raw & 7) * 64 + (raw >> 3);
    const int m   = wg >> 5;          // 0..15
    const int ob  = (wg >> 2) & 7;    // 0..7
    const int bb  = wg & 3;           // 0..3

    const int wr = w >> 1, wc = w & 1;   // wave -> 64x64 quadrant of the 128x128 tile

    f32x4 acc[4][4];
#pragma unroll
    for (int mi = 0; mi < 4; ++mi)
#pragma unroll
        for (int ni = 0; ni < 4; ++ni)
            acc[mi][ni] = (f32x4){0.f, 0.f, 0.f, 0.f};

    // --- staging maps ---
    // A: per ld(0..3): row = ld*32 + t/8, k0 = (t&7)*4  (float4 along k, coalesced 128B/row)
    const int a_row = t >> 3;
    const int a_k0  = (t & 7) * 4;
    // B: wave covers o-half och=w&1 (lane o = och*64+l, 256B coalesced rows),
    //    k-chunk ic = (w>>1) + 2*ld; thread loads 4 scalars down column o -> b64 LDS write.
    const int och    = w & 1;
    const int o_lane = och * 64 + l;               // 0..127 within o-tile
    const int bswz   = ((o_lane >> 3) & 1) << 3;   // XOR swizzle bit for this column

    const size_t x_base = ((size_t)(bb * BM) * NMASK + m) * IN_D;
    const size_t k_base = (size_t)(ob * BN) + o_lane;                       // into Kn rows
    const size_t mk_base = ((size_t)m * IN_D) * OUT_D + (size_t)(ob * BN) + o_lane;

    for (int kt = 0; kt < IN_D; kt += BK) {
        // ---- global loads into registers (issue all before barrier) ----
        float4 av[4];
#pragma unroll
        for (int ld = 0; ld < 4; ++ld) {
            const int row = ld * 32 + a_row;
            av[ld] = *(const float4*)(X + x_base + (size_t)row * (NMASK * IN_D) + kt + a_k0);
        }
        float bv[4][4];
#pragma unroll
        for (int ld = 0; ld < 4; ++ld) {
            const int ic = (w >> 1) + 2 * ld;      // k-chunk 0..7
#pragma unroll
            for (int j = 0; j < 4; ++j) {
                const int i = kt + ic * 4 + j;
                const float kv = Kn[(size_t)i * OUT_D + k_base];
                const float mv = Mk[mk_base + (size_t)i * OUT_D];
                bv[ld][j] = kv * mv;               // fp32 product, single bf16 rounding below
            }
        }

        __syncthreads();   // previous iteration's frag reads done before overwrite

        // ---- LDS writes ----
#pragma unroll
        for (int ld = 0; ld < 4; ++ld) {
            const int row = ld * 32 + a_row;
            *(ushort4*)(&As[row * BKP + a_k0]) =
                pack4(av[ld].x, av[ld].y, av[ld].z, av[ld].w);
        }
#pragma unroll
        for (int ld = 0; ld < 4; ++ld) {
            const int ic = (w >> 1) + 2 * ld;
            *(ushort4*)(&Bs[o_lane * BKP + ((ic * 4) ^ bswz)]) =
                pack4(bv[ld][0], bv[ld][1], bv[ld][2], bv[ld][3]);
        }

        __syncthreads();

        // ---- fragments + MFMA ----
        bf16x8 afrag[4], bfrag[4];
        const int kg = (l >> 4) * 8;               // k-group of this lane
#pragma unroll
        for (int mi = 0; mi < 4; ++mi) {
            const int r = wr * 64 + mi * 16 + (l & 15);
            afrag[mi] = *(const bf16x8*)(&As[r * BKP + kg]);
        }
#pragma unroll
        for (int ni = 0; ni < 4; ++ni) {
            const int n = wc * 64 + ni * 16 + (l & 15);
            const int f = ((n >> 3) & 1) << 3;
            bfrag[ni] = *(const bf16x8*)(&Bs[n * BKP + (kg ^ f)]);
        }
#pragma unroll
        for (int mi = 0; mi < 4; ++mi)
#pragma unroll
            for (int ni = 0; ni < 4; ++ni)
                acc[mi][ni] = __builtin_amdgcn_mfma_f32_16x16x32_bf16(
                    afrag[mi], bfrag[ni], acc[mi][ni], 0, 0, 0);
    }

    // ---- epilogue: C/D layout col = l&15, row = (l>>4)*4 + reg ----
    const int r0 = bb * BM + wr * 64 + (l >> 4) * 4;
    const int c0 = ob * BN + wc * 64 + (l & 15);
#pragma unroll
    for (int mi = 0; mi < 4; ++mi) {
#pragma unroll
        for (int j = 0; j < 4; ++j) {
            const size_t row = (size_t)(r0 + mi * 16 + j);
            float* op = Out + (row * NMASK + m) * OUT_D + c0;
#pragma unroll
            for (int ni = 0; ni < 4; ++ni)
                op[ni * 16] = acc[mi][ni][j];
        }
    }
}

extern "C" void kernel_launch(void* const* d_in, const int* in_sizes, int n_in,
                              void* d_out, int out_size, void* d_ws, size_t ws_size,
                              hipStream_t stream) {
    (void)in_sizes; (void)n_in; (void)d_ws; (void)ws_size; (void)out_size;
    const float* X  = (const float*)d_in[0];
    const float* Kn = (const float*)d_in[1];
    const float* Mk = (const float*)d_in[2];
    float* Out = (float*)d_out;

    const int nblocks = (BATCH / BM) * (OUT_D / BN) * NMASK;  // 4*8*16 = 512
    mdl_mfma_kernel<<<nblocks, THREADS, 0, stream>>>(X, Kn, Mk, Out);
}